// Round 21
// baseline (644.924 us; speedup 1.0000x reference)
//
#include <hip/hip_runtime.h>

// ---------------------------------------------------------------------------
// GCN 4-layer inference.
//  - k_prep: edge count+rank (atomics) + x->fp16 (padded to 512) + weight
//    decompose, all fused (streaming overlaps atomic latency).
//  - GEMMs: K-phased resident-W; phase re-stages are REG-staged (loads issued
//    a phase early, ds_write after barrier -> barriers are pure sync).
//    Layer1: 224-col block, 4 phases of 128, fp16 A (pad-zeroed), fused CSR
//    fill. Layer2: 128-col block, 2 phases. Layer3: 64-col block, 1 phase.
//  - Aggregation: CSR gather, flat lane mapping, 8-deep software-pipelined.
// ---------------------------------------------------------------------------

#define DEV __device__ __forceinline__

typedef __attribute__((ext_vector_type(8))) short short8;
typedef __attribute__((ext_vector_type(8))) _Float16 f16x8;
typedef __attribute__((ext_vector_type(4))) float f32x4;
typedef __attribute__((ext_vector_type(4))) _Float16 f16x4;

DEV void gload_lds16(const void* g, void* l) {     // 16-B DMA global -> LDS
    __builtin_amdgcn_global_load_lds(
        (const __attribute__((address_space(1))) unsigned int*)g,
        (__attribute__((address_space(3))) unsigned int*)l, 16, 0, 0);
}

// ---------------- fused prep: count+rank, x->fp16, weight decompose ----------------

__global__ void k_prep(const int* __restrict__ dst, int* __restrict__ cnt,
                       int* __restrict__ rank, int E,
                       const float* __restrict__ x, _Float16* __restrict__ x16, int N,
                       const float* __restrict__ W1, unsigned short* __restrict__ wh1,
                       const float* __restrict__ W1b, unsigned short* __restrict__ wh2,
                       unsigned short* __restrict__ wl2,
                       const float* __restrict__ W2b, unsigned short* __restrict__ wh3,
                       unsigned short* __restrict__ wl3) {
    const int SZ1 = 224 * 512, SZ2 = 128 * 256, SZ3 = 64 * 128;
    const int SZX = N * 64;                         // 8 fp16 per thread, stride 512
    int i = blockIdx.x * 256 + threadIdx.x;
    if (i < E) {
        rank[i] = atomicAdd(&cnt[dst[i]], 1);
        return;
    }
    i -= E;
    if (i < SZX) {                                  // x fp32 -> fp16, pad 500->512
        int r = i >> 6, c = i & 63;
        int k0 = c * 8;
        f16x8 o;
#pragma unroll
        for (int j = 0; j < 8; ++j) {
            int k = k0 + j;
            o[j] = (k < 500) ? (_Float16)x[(size_t)r * 500 + k] : (_Float16)0.f;
        }
        *(f16x8*)&x16[(size_t)r * 512 + k0] = o;
        return;
    }
    i -= SZX;
    if (i < SZ1) {                                  // W1 -> fp16 single (224x512)
        int r = i >> 9, k = i & 511;
        float v = (r < 200 && k < 500) ? W1[r * 500 + k] : 0.f;
        wh1[i] = __builtin_bit_cast(unsigned short, (_Float16)v);
        return;
    }
    i -= SZ1;
    if (i < SZ2) {                                  // W1b -> hi/lo (128x256)
        int r = i >> 8, k = i & 255;
        float v = (r < 100 && k < 200) ? W1b[r * 200 + k] : 0.f;
        _Float16 h = (_Float16)v;
        _Float16 l = (_Float16)((v - (float)h) * 2048.0f);
        wh2[i] = __builtin_bit_cast(unsigned short, h);
        wl2[i] = __builtin_bit_cast(unsigned short, l);
        return;
    }
    i -= SZ2;
    if (i < SZ3) {                                  // W2b -> hi/lo (64x128)
        int r = i >> 7, k = i & 127;
        float v = (r < 40 && k < 100) ? W2b[r * 100 + k] : 0.f;
        _Float16 h = (_Float16)v;
        _Float16 l = (_Float16)((v - (float)h) * 2048.0f);
        wh3[i] = __builtin_bit_cast(unsigned short, h);
        wl3[i] = __builtin_bit_cast(unsigned short, l);
    }
}

// ---------------- scan: row_start from cnt+1; dinv ----------------

__global__ void k_scan1(const int* __restrict__ cnt, int* __restrict__ row_start,
                        int* __restrict__ partial, float* __restrict__ dinv, int n) {
    __shared__ int sdata[256];
    int base = blockIdx.x * 1024;
    int t = threadIdx.x;
    int v[4]; int sum = 0;
#pragma unroll
    for (int j = 0; j < 4; ++j) {
        int idx = base + t * 4 + j;
        v[j] = (idx < n) ? (cnt[idx] + 1) : 0;
        if (idx < n) dinv[idx] = rsqrtf((float)v[j]);
        sum += v[j];
    }
    sdata[t] = sum;
    __syncthreads();
    for (int off = 1; off < 256; off <<= 1) {
        int x = (t >= off) ? sdata[t - off] : 0;
        __syncthreads();
        sdata[t] += x;
        __syncthreads();
    }
    int excl = sdata[t] - sum;
#pragma unroll
    for (int j = 0; j < 4; ++j) {
        int idx = base + t * 4 + j;
        if (idx < n) row_start[idx] = excl;
        excl += v[j];
    }
    if (t == 255) partial[blockIdx.x] = sdata[255];
}

__global__ void k_scan2(int* __restrict__ partial, int nb) {
    __shared__ int s[128];
    int t = threadIdx.x;
    int v = (t < nb) ? partial[t] : 0;
    s[t] = v;
    __syncthreads();
    for (int off = 1; off < 128; off <<= 1) {
        int x = (t >= off) ? s[t - off] : 0;
        __syncthreads();
        s[t] += x;
        __syncthreads();
    }
    if (t < nb) partial[t] = s[t] - v;
}

__global__ void k_scan3(int* __restrict__ row_start, const int* __restrict__ partial,
                        int n, int total) {
    int i = blockIdx.x * 256 + threadIdx.x;
    if (i < n) row_start[i] += partial[i >> 10];
    if (i == 0) row_start[n] = total;
}

// ---------------- K-phased resident-W MFMA GEMM ----------------
// Phase 0 staged via DMA; re-stages REG-staged: W(p+1) loads issued at phase-p
// start, ds_write after barrier (pure-sync barriers). Optional fused CSR fill.

template <int NFC, int KPH, int NPH, int HILO, int DOFILL>
__global__ __launch_bounds__(512, 4)
void gemm_res(const _Float16* __restrict__ A, int lda, int M, int K,
              const unsigned short* __restrict__ Wh,
              const unsigned short* __restrict__ Wl,
              const float* __restrict__ dinv,
              _Float16* __restrict__ H16, int ldh, int Nout,
              const int* __restrict__ fsrc, const int* __restrict__ fdst,
              const int* __restrict__ frows, const int* __restrict__ fcnt,
              const int* __restrict__ frank, int* __restrict__ fcsr, int fE, int fN) {
    constexpr int NPAD = NFC * 16;
    constexpr int KP   = KPH * NPH;            // full padded K
    constexpr int CHH  = NPAD * KPH / 8;       // 16-B chunks per half per phase
    constexpr int CHT  = CHH * (1 + HILO);     // total chunks (divisible by 512)
    constexpr int NIT  = CHT / 512;
    constexpr int SB   = NPAD * 64;            // LDS bytes per K-step
    constexpr int HB   = CHH * 16;             // lo-half byte offset
    constexpr int SPP  = KPH / 32;             // steps per phase
    constexpr int NS   = SPP * NPH;
    constexpr int D    = 2;                    // A prefetch depth
    __shared__ char lds[CHT * 16];

    const int tid  = threadIdx.x;
    const int wv   = tid >> 6;
    const int lane = tid & 63;
    const int lr   = lane & 15;
    const int kq   = lane >> 4;
    const int m0   = blockIdx.y * 128;
    const int col0 = blockIdx.x * NPAD;

    // ---- fused CSR fill slice ----
    if constexpr (DOFILL) {
        int total = fE + fN;
        int nb    = gridDim.y;
        int per   = (total + nb - 1) / nb;
        int base  = blockIdx.y * per;
        int end   = base + per; if (end > total) end = total;
        for (int i = base + tid; i < end; i += 512) {
            int s, pos;
            if (i < fE) {
                s = fsrc[i];
                pos = frows[fdst[i]] + frank[i];
            } else {
                s = i - fE;
                pos = frows[s] + fcnt[s];
            }
            fcsr[pos] = s;
        }
    }

    const unsigned short* WhB = Wh + (size_t)col0 * KP;
    const unsigned short* WlB = Wl + (size_t)col0 * KP;

    // per-thread chunk decode (compile-time indexed arrays)
    const unsigned short* gpb[NIT];            // global src base (phase 0)
    int ldo_[NIT];                             // linear LDS byte offset
#pragma unroll
    for (int i = 0; i < NIT; ++i) {
        int c  = tid + i * 512;
        int h  = (HILO && c >= CHH) ? 1 : 0;
        int cc = c - h * CHH;
        int st = cc / (NPAD * 4);
        int rm = cc - st * (NPAD * 4);
        int r  = rm >> 2;
        int sl = rm & 3;
        int gs = sl ^ (r & 3);                 // involutory slot swizzle (source side)
        gpb[i] = (h ? WlB : WhB) + (size_t)r * KP + st * 32 + gs * 8;
        ldo_[i] = c * 16;
    }

    // ---- phase-0 staging via DMA ----
#pragma unroll
    for (int i = 0; i < NIT; ++i) gload_lds16(gpb[i], lds + ldo_[i]);

    int arow = m0 + wv * 16 + lr;
    if (arow >= M) arow = M - 1;               // clamp; stores masked
    const _Float16* Arow = A + (size_t)arow * lda;

    auto loadA = [&](int s) -> short8 {        // K padded/zeroed -> unguarded
        return *(const short8*)((const unsigned short*)Arow + s * 32 + kq * 8);
    };

    short8 hb[D];
#pragma unroll
    for (int p = 0; p < D; ++p)
        if (p < NS) hb[p] = loadA(p);

    f32x4 ac[NFC], al[NFC];
#pragma unroll
    for (int f = 0; f < NFC; ++f) {
        ac[f] = (f32x4){0.f, 0.f, 0.f, 0.f};
        al[f] = (f32x4){0.f, 0.f, 0.f, 0.f};
    }

    __syncthreads();                           // phase-0 W resident

    const int ro = lr * 64 + ((kq ^ (lr & 3)) << 4);   // swizzled read offset

    uint4 wreg[NIT > 0 ? NIT : 1];

#pragma unroll
    for (int p = 0; p < NPH; ++p) {
        // issue next-phase W loads into registers (cover under this phase's MFMAs)
        if (p + 1 < NPH) {
#pragma unroll
            for (int i = 0; i < NIT; ++i)
                wreg[i] = *(const uint4*)(gpb[i] + (size_t)(p + 1) * KPH);
        }
#pragma unroll
        for (int sl = 0; sl < SPP; ++sl) {
            const int s = p * SPP + sl;
            f16x8 a0 = __builtin_bit_cast(f16x8, hb[s % D]);
            if (s + D < NS) hb[s % D] = loadA(s + D);

            const char* bb = lds + sl * SB;
#pragma unroll
            for (int f = 0; f < NFC; ++f) {
                f16x8 bh = __builtin_bit_cast(f16x8, *(const short8*)(bb + f * 1024 + ro));
                ac[f] = __builtin_amdgcn_mfma_f32_16x16x32_f16(a0, bh, ac[f], 0, 0, 0);
                if constexpr (HILO) {
                    f16x8 bl = __builtin_bit_cast(f16x8, *(const short8*)(bb + HB + f * 1024 + ro));
                    al[f] = __builtin_amdgcn_mfma_f32_16x16x32_f16(a0, bl, al[f], 0, 0, 0);
                }
            }
        }
        if (p + 1 < NPH) {                     // pure-sync re-stage
            __syncthreads();                   // all reads of phase p done
#pragma unroll
            for (int i = 0; i < NIT; ++i) *(uint4*)(lds + ldo_[i]) = wreg[i];
            __syncthreads();                   // phase p+1 W resident
        }
    }

    // ---- store: D row=(lane>>4)*4+j, col=lane&15; scale dinv, cast fp16 ----
    const int rbase = m0 + wv * 16 + kq * 4;
    float dv[4];
#pragma unroll
    for (int j = 0; j < 4; ++j) {
        int row = rbase + j;
        dv[j] = (row < M) ? dinv[row] : 0.f;
    }
#pragma unroll
    for (int f = 0; f < NFC; ++f) {
        int col = col0 + f * 16 + lr;
        if (col >= Nout) continue;
#pragma unroll
        for (int j = 0; j < 4; ++j) {
            int row = rbase + j;
            if (row >= M) continue;
            float v = ac[f][j];
            if constexpr (HILO) v += al[f][j] * (1.0f / 2048.0f);
            H16[(size_t)row * ldh + col] = (_Float16)(v * dv[j]);
        }
    }
}

// ---------------- aggregation: out = dinv[d] * sum_e h16[src_e] + b -----------------
// flat mapping, 8-deep + 4-deep software-pipelined gather

template <int F, int VEC, bool RELU>
__global__ __launch_bounds__(256)
void agg_f16(const _Float16* __restrict__ h, const int* __restrict__ row_start,
             const int* __restrict__ csr_src, const float* __restrict__ dinv,
             const float* __restrict__ bias, _Float16* __restrict__ out, int n,
             int ldo) {
    constexpr int LPN = F / VEC;
    int gid  = blockIdx.x * 256 + threadIdx.x;
    int node = gid / LPN;
    int fi   = gid - node * LPN;
    if (node >= n) return;
    int f = fi * VEC;
    const _Float16* hf = h + f;

    f32x4 acc0 = {0.f, 0.f, 0.f, 0.f};
    f32x4 acc1 = {0.f, 0.f, 0.f, 0.f};

    auto addv = [&](const _Float16* p) {
        if constexpr (VEC == 8) {
            f16x8 v = *(const f16x8*)p;
            f16x4 vl, vh;
#pragma unroll
            for (int j = 0; j < 4; ++j) { vl[j] = v[j]; vh[j] = v[4 + j]; }
            acc0 += __builtin_convertvector(vl, f32x4);
            acc1 += __builtin_convertvector(vh, f32x4);
        } else {
            f16x4 v = *(const f16x4*)p;
            acc0 += __builtin_convertvector(v, f32x4);
        }
    };

    int e0 = row_start[node], e1 = row_start[node + 1];
    int e = e0;
    for (; e + 8 <= e1; e += 8) {
        int s0 = csr_src[e + 0], s1 = csr_src[e + 1];
        int s2 = csr_src[e + 2], s3 = csr_src[e + 3];
        int s4 = csr_src[e + 4], s5 = csr_src[e + 5];
        int s6 = csr_src[e + 6], s7 = csr_src[e + 7];
        const _Float16* p0 = &hf[(size_t)s0 * F];
        const _Float16* p1 = &hf[(size_t)s1 * F];
        const _Float16* p2 = &hf[(size_t)s2 * F];
        const _Float16* p3 = &hf[(size_t)s3 * F];
        const _Float16* p4 = &hf[(size_t)s4 * F];
        const _Float16* p5 = &hf[(size_t)s5 * F];
        const _Float16* p6 = &hf[(size_t)s6 * F];
        const _Float16* p7 = &hf[(size_t)s7 * F];
        addv(p0); addv(p1); addv(p2); addv(p3);
        addv(p4); addv(p5); addv(p6); addv(p7);
    }
    for (; e + 4 <= e1; e += 4) {
        int s0 = csr_src[e + 0], s1 = csr_src[e + 1];
        int s2 = csr_src[e + 2], s3 = csr_src[e + 3];
        const _Float16* p0 = &hf[(size_t)s0 * F];
        const _Float16* p1 = &hf[(size_t)s1 * F];
        const _Float16* p2 = &hf[(size_t)s2 * F];
        const _Float16* p3 = &hf[(size_t)s3 * F];
        addv(p0); addv(p1); addv(p2); addv(p3);
    }
    for (; e < e1; ++e) addv(&hf[(size_t)csr_src[e] * F]);

    float dn = dinv[node];
    if constexpr (VEC == 8) {
        f32x4 b0 = *(const f32x4*)&bias[f];
        f32x4 b1 = *(const f32x4*)&bias[f + 4];
        acc0 = acc0 * dn + b0;
        acc1 = acc1 * dn + b1;
        if (RELU) {
#pragma unroll
            for (int j = 0; j < 4; ++j) { acc0[j] = fmaxf(acc0[j], 0.f); acc1[j] = fmaxf(acc1[j], 0.f); }
        }
        f16x8 o;
#pragma unroll
        for (int j = 0; j < 4; ++j) { o[j] = (_Float16)acc0[j]; o[4 + j] = (_Float16)acc1[j]; }
        *(f16x8*)&out[(size_t)node * ldo + f] = o;
    } else {
        f32x4 b4 = *(const f32x4*)&bias[f];
        acc0 = acc0 * dn + b4;
        if (RELU) {
#pragma unroll
            for (int j = 0; j < 4; ++j) acc0[j] = fmaxf(acc0[j], 0.f);
        }
        f16x4 o;
#pragma unroll
        for (int j = 0; j < 4; ++j) o[j] = (_Float16)acc0[j];
        *(f16x4*)&out[(size_t)node * ldo + f] = o;
    }
}

// ---------------- tiny layer-4 helpers ----------------

__global__ void gemm_small(const _Float16* __restrict__ A, const float* __restrict__ B,
                           const float* __restrict__ dinv, float* __restrict__ C,
                           int M, int K) {
    int m = blockIdx.x * 256 + threadIdx.x;
    if (m >= M) return;
    float a0 = 0.f, a1 = 0.f, a2 = 0.f;
    for (int k = 0; k < K; ++k) {
        float a = (float)A[(size_t)m * K + k];
        a0 += a * B[0 * K + k];
        a1 += a * B[1 * K + k];
        a2 += a * B[2 * K + k];
    }
    float dv = dinv[m];
    C[(size_t)m * 3 + 0] = a0 * dv;
    C[(size_t)m * 3 + 1] = a1 * dv;
    C[(size_t)m * 3 + 2] = a2 * dv;
}

__global__ void agg_f3(const float* __restrict__ h, const int* __restrict__ row_start,
                       const int* __restrict__ csr_src, const float* __restrict__ dinv,
                       const float* __restrict__ bias, float* __restrict__ out, int n) {
    int i = blockIdx.x * 256 + threadIdx.x;
    if (i >= n * 3) return;
    int node = i / 3;
    int f = i - node * 3;
    float acc = 0.f;
    int e1 = row_start[node + 1];
    for (int e = row_start[node]; e < e1; ++e) {
        int s = csr_src[e];
        acc += h[(size_t)s * 3 + f];
    }
    out[i] = acc * dinv[node] + bias[f];
}

// ---------------------------------------------------------------------------

extern "C" void kernel_launch(void* const* d_in, const int* in_sizes, int n_in,
                              void* d_out, int out_size, void* d_ws, size_t ws_size,
                              hipStream_t stream) {
    const float* x   = (const float*)d_in[0];
    const int*   ei  = (const int*)d_in[1];
    const float* W1  = (const float*)d_in[2];
    const float* b1  = (const float*)d_in[3];
    const float* W1b = (const float*)d_in[4];
    const float* b1b = (const float*)d_in[5];
    const float* W2b = (const float*)d_in[6];
    const float* b2b = (const float*)d_in[7];
    const float* W2  = (const float*)d_in[8];
    const float* b2  = (const float*)d_in[9];
    float* out = (float*)d_out;

    const int F_IN = 500, H1 = 200, H2 = 100, H3 = 40;
    const int N = in_sizes[0] / F_IN;
    const int E = in_sizes[1] / 2;
    const int* src = ei;
    const int* dst = ei + E;

    size_t off = 0;
    auto alloc = [&](size_t bytes) -> void* {
        void* p = (char*)d_ws + off;
        off += (bytes + 255) & ~(size_t)255;
        return p;
    };
    int*   cnt       = (int*)  alloc((size_t)N * 4);
    int*   row_start = (int*)  alloc((size_t)(N + 1) * 4);
    int*   rank      = (int*)  alloc((size_t)E * 4);
    int*   partial   = (int*)  alloc(128 * 4);
    float* dinv      = (float*)alloc((size_t)N * 4);
    int*   csr_src   = (int*)  alloc((size_t)(E + N) * 4);
    unsigned short* wh1 = (unsigned short*)alloc(224 * 512 * 2);
    unsigned short* wh2 = (unsigned short*)alloc(128 * 256 * 2);
    unsigned short* wl2 = (unsigned short*)alloc(128 * 256 * 2);
    unsigned short* wh3 = (unsigned short*)alloc( 64 * 128 * 2);
    unsigned short* wl3 = (unsigned short*)alloc( 64 * 128 * 2);
    _Float16* x16  = (_Float16*)alloc((size_t)N * 512 * 2);  // fp16 x (padded); act16 aliases
    _Float16* h16  = (_Float16*)alloc((size_t)N * H1 * 2);   // gemm outputs
    float*    bufC = (float*)   alloc((size_t)N * 3 * 4);
    _Float16* act16 = x16;     // x16 dead after layer-1 GEMM; reuse for activations

    int gN = (N + 255) / 256;
    int nb = (N + 1023) / 1024;

    // --- prep: zero cnt, then fused count+rank / x->fp16 / weight decompose ---
    hipMemsetAsync(cnt, 0, (size_t)N * 4, stream);
    {
        long long total = (long long)E + (long long)N * 64
                        + 224 * 512 + 128 * 256 + 64 * 128;
        k_prep<<<(int)((total + 255) / 256), 256, 0, stream>>>(
            dst, cnt, rank, E, x, x16, N, W1, wh1, W1b, wh2, wl2, W2b, wh3, wl3);
    }
    k_scan1<<<nb, 256, 0, stream>>>(cnt, row_start, partial, dinv, N);
    k_scan2<<<1, 128, 0, stream>>>(partial, nb);
    k_scan3<<<gN, 256, 0, stream>>>(row_start, partial, N, E + N);

    const int gR = (N + 127) / 128;   // BM = 128

    // --- layer 1: 224-col block, 4 K-phases of 128, fp16 A + FUSED csr fill ---
    gemm_res<14, 128, 4, 0, 1><<<dim3(1, gR), 512, 0, stream>>>(
        x16, 512, N, 512, wh1, wh1, dinv, h16, H1, H1,
        src, dst, row_start, cnt, rank, csr_src, E, N);
    {
        long long thr = (long long)N * 25;             // LPN = 200/8 = 25
        agg_f16<200, 8, true><<<(int)((thr + 255) / 256), 256, 0, stream>>>(
            h16, row_start, csr_src, dinv, b1, act16, N, 200);
    }
    // --- layer 2: ONE 128-col block, W hi/lo, K padded 256, 2 phases ---
    gemm_res<8, 128, 2, 1, 0><<<dim3(1, gR), 512, 0, stream>>>(
        act16, 200, N, H1, wh2, wl2, dinv, h16, H2, H2,
        nullptr, nullptr, nullptr, nullptr, nullptr, nullptr, 0, 0);
    {
        long long thr = (long long)N * 25;             // LPN = 100/4 = 25
        agg_f16<100, 4, true><<<(int)((thr + 255) / 256), 256, 0, stream>>>(
            h16, row_start, csr_src, dinv, b1b, act16, N, 112);
    }
    // --- layer 3: 1 col-block of 64, W hi/lo, single phase (A stride 112) ---
    gemm_res<4, 128, 1, 1, 0><<<dim3(1, gR), 512, 0, stream>>>(
        act16, 112, N, H2, wh3, wl3, dinv, h16, H3, H3,
        nullptr, nullptr, nullptr, nullptr, nullptr, nullptr, 0, 0);
    {
        long long thr = (long long)N * 5;              // LPN = 40/8 = 5
        agg_f16<40, 8, true><<<(int)((thr + 255) / 256), 256, 0, stream>>>(
            h16, row_start, csr_src, dinv, b2b, act16, N, 40);
    }
    // --- layer 4 ---
    gemm_small<<<(N + 255) / 256, 256, 0, stream>>>(act16, W2, dinv, bufC, N, H3);
    agg_f3<<<(N * 3 + 255) / 256, 256, 0, stream>>>(bufC, row_start, csr_src, dinv,
                                                    b2, out, N);
}

// Round 22
// 490.034 us; speedup vs baseline: 1.3161x; 1.3161x over previous
//
#include <hip/hip_runtime.h>

// ---------------------------------------------------------------------------
// GCN 4-layer inference.  (r18 configuration + 8-deep agg gather)
//  - CSR build: rank-based; k_count + weight-decompose fused into k_prep;
//    csr fill FUSED into layer-1 GEMM prologue.
//  - GEMMs: K-phased resident-W (layer1: one 224-col block, 4 phases of 128,
//    LDS 57.3KB; barrier-free K-loop within phase), 8 waves x 16 rows,
//    depth-2 rotating A prefetch. Layers 2/3: W fp16 hi+lo*2^-11.
//  - Activations between layers fp16.
//  - Aggregation: CSR gather, 16B/lane where F allows, 8-deep pipelined.
// ---------------------------------------------------------------------------

#define DEV __device__ __forceinline__

typedef __attribute__((ext_vector_type(8))) short short8;
typedef __attribute__((ext_vector_type(8))) _Float16 f16x8;
typedef __attribute__((ext_vector_type(4))) float f32x4;
typedef __attribute__((ext_vector_type(4))) _Float16 f16x4;

DEV void gload_lds16(const void* g, void* l) {     // 16-B DMA global -> LDS
    __builtin_amdgcn_global_load_lds(
        (const __attribute__((address_space(1))) unsigned int*)g,
        (__attribute__((address_space(3))) unsigned int*)l, 16, 0, 0);
}

// ---------------- fused prep: edge count+rank, weight cvt/decompose ----------------

__global__ void k_prep(const int* __restrict__ dst, int* __restrict__ cnt,
                       int* __restrict__ rank, int E,
                       const float* __restrict__ W1, unsigned short* __restrict__ wh1,
                       const float* __restrict__ W1b, unsigned short* __restrict__ wh2,
                       unsigned short* __restrict__ wl2,
                       const float* __restrict__ W2b, unsigned short* __restrict__ wh3,
                       unsigned short* __restrict__ wl3) {
    const int SZ1 = 224 * 512, SZ2 = 128 * 256, SZ3 = 64 * 128;
    int i = blockIdx.x * 256 + threadIdx.x;
    if (i < E) {
        rank[i] = atomicAdd(&cnt[dst[i]], 1);
        return;
    }
    i -= E;
    if (i < SZ1) {                                  // W1 -> fp16 single (224x512)
        int r = i >> 9, k = i & 511;
        float x = (r < 200 && k < 500) ? W1[r * 500 + k] : 0.f;
        wh1[i] = __builtin_bit_cast(unsigned short, (_Float16)x);
        return;
    }
    i -= SZ1;
    if (i < SZ2) {                                  // W1b -> hi/lo (128x256)
        int r = i >> 8, k = i & 255;
        float x = (r < 100 && k < 200) ? W1b[r * 200 + k] : 0.f;
        _Float16 h = (_Float16)x;
        _Float16 l = (_Float16)((x - (float)h) * 2048.0f);
        wh2[i] = __builtin_bit_cast(unsigned short, h);
        wl2[i] = __builtin_bit_cast(unsigned short, l);
        return;
    }
    i -= SZ2;
    if (i < SZ3) {                                  // W2b -> hi/lo (64x128)
        int r = i >> 7, k = i & 127;
        float x = (r < 40 && k < 100) ? W2b[r * 100 + k] : 0.f;
        _Float16 h = (_Float16)x;
        _Float16 l = (_Float16)((x - (float)h) * 2048.0f);
        wh3[i] = __builtin_bit_cast(unsigned short, h);
        wl3[i] = __builtin_bit_cast(unsigned short, l);
    }
}

// ---------------- scan: row_start from cnt+1; dinv ----------------

__global__ void k_scan1(const int* __restrict__ cnt, int* __restrict__ row_start,
                        int* __restrict__ partial, float* __restrict__ dinv, int n) {
    __shared__ int sdata[256];
    int base = blockIdx.x * 1024;
    int t = threadIdx.x;
    int v[4]; int sum = 0;
#pragma unroll
    for (int j = 0; j < 4; ++j) {
        int idx = base + t * 4 + j;
        v[j] = (idx < n) ? (cnt[idx] + 1) : 0;
        if (idx < n) dinv[idx] = rsqrtf((float)v[j]);
        sum += v[j];
    }
    sdata[t] = sum;
    __syncthreads();
    for (int off = 1; off < 256; off <<= 1) {
        int x = (t >= off) ? sdata[t - off] : 0;
        __syncthreads();
        sdata[t] += x;
        __syncthreads();
    }
    int excl = sdata[t] - sum;
#pragma unroll
    for (int j = 0; j < 4; ++j) {
        int idx = base + t * 4 + j;
        if (idx < n) row_start[idx] = excl;
        excl += v[j];
    }
    if (t == 255) partial[blockIdx.x] = sdata[255];
}

__global__ void k_scan2(int* __restrict__ partial, int nb) {
    __shared__ int s[128];
    int t = threadIdx.x;
    int v = (t < nb) ? partial[t] : 0;
    s[t] = v;
    __syncthreads();
    for (int off = 1; off < 128; off <<= 1) {
        int x = (t >= off) ? s[t - off] : 0;
        __syncthreads();
        s[t] += x;
        __syncthreads();
    }
    if (t < nb) partial[t] = s[t] - v;
}

__global__ void k_scan3(int* __restrict__ row_start, const int* __restrict__ partial,
                        int n, int total) {
    int i = blockIdx.x * 256 + threadIdx.x;
    if (i < n) row_start[i] += partial[i >> 10];
    if (i == 0) row_start[n] = total;
}

// ---------------- K-phased resident-W MFMA GEMM (+ optional fused CSR fill) --------

struct A8 { f32x4 lo, hi; };

template <int NFC, int KPH, int NPH, int HILO, int MODE, int DOFILL, typename AT>
__global__ __launch_bounds__(512, 4)
void gemm_res(const AT* __restrict__ A, int lda, int M, int K,
              const unsigned short* __restrict__ Wh,
              const unsigned short* __restrict__ Wl,
              const float* __restrict__ dinv,
              _Float16* __restrict__ H16, int ldh, int Nout,
              const int* __restrict__ fsrc, const int* __restrict__ fdst,
              const int* __restrict__ frows, const int* __restrict__ fcnt,
              const int* __restrict__ frank, int* __restrict__ fcsr, int fE, int fN) {
    constexpr int NPAD = NFC * 16;
    constexpr int KP   = KPH * NPH;            // full padded K
    constexpr int CHH  = NPAD * KPH / 8;       // 16-B chunks per half per phase
    constexpr int CHT  = CHH * (1 + HILO);
    constexpr int NIT  = (CHT + 511) / 512;
    constexpr int SB   = NPAD * 64;            // LDS bytes per K-step
    constexpr int HB   = CHH * 16;             // lo-half byte offset
    constexpr int SPP  = KPH / 32;             // steps per phase
    constexpr int NS   = SPP * NPH;
    constexpr int D    = 2;                    // A prefetch depth
    __shared__ char lds[CHT * 16];

    const int tid  = threadIdx.x;
    const int wv   = tid >> 6;
    const int lane = tid & 63;
    const int lr   = lane & 15;
    const int kq   = lane >> 4;
    const int m0   = blockIdx.y * 128;
    const int col0 = blockIdx.x * NPAD;

    // ---- fused CSR fill slice ----
    if constexpr (DOFILL) {
        int total = fE + fN;
        int nb    = gridDim.y;
        int per   = (total + nb - 1) / nb;
        int base  = blockIdx.y * per;
        int end   = base + per; if (end > total) end = total;
        for (int i = base + tid; i < end; i += 512) {
            int s, pos;
            if (i < fE) {
                s = fsrc[i];
                pos = frows[fdst[i]] + frank[i];
            } else {
                s = i - fE;
                pos = frows[s] + fcnt[s];
            }
            fcsr[pos] = s;
        }
    }

    const unsigned short* WhB = Wh + (size_t)col0 * KP;
    const unsigned short* WlB = Wl + (size_t)col0 * KP;

    auto stageW = [&](int p) {
#pragma unroll
        for (int i = 0; i < NIT; ++i) {
            int c = tid + i * 512;
            if ((CHT % 512 == 0) || (c < CHT)) {
                int h  = (HILO && c >= CHH) ? 1 : 0;
                int cc = c - h * CHH;
                int st = cc / (NPAD * 4);
                int rm = cc - st * (NPAD * 4);
                int r  = rm >> 2;
                int sl = rm & 3;
                int gs = sl ^ (r & 3);         // involutory slot swizzle (source side)
                const unsigned short* gp = (h ? WlB : WhB)
                    + (size_t)r * KP + p * KPH + st * 32 + gs * 8;
                gload_lds16(gp, lds + (size_t)c * 16);
            }
        }
    };

    int arow = m0 + wv * 16 + lr;
    if (arow >= M) arow = M - 1;               // clamp; stores masked
    const AT* Arow = A + (size_t)arow * lda;

    auto loadA32 = [&](int s) -> A8 {
        A8 o;
        int kb = s * 32 + kq * 8;
        if (kb + 8 <= K) {
            const float* ap = (const float*)Arow + kb;
            o.lo = *(const f32x4*)ap;
            o.hi = *(const f32x4*)(ap + 4);
        } else {
#pragma unroll
            for (int i = 0; i < 4; ++i) {
                int k0 = kb + i, k1 = kb + 4 + i;
                o.lo[i] = (k0 < K) ? (float)Arow[k0] : 0.f;
                o.hi[i] = (k1 < K) ? (float)Arow[k1] : 0.f;
            }
        }
        return o;
    };
    auto loadA16 = [&](int s) -> short8 {
        int kb = s * 32 + kq * 8;
        if (kb + 8 <= K) return *(const short8*)((const unsigned short*)Arow + kb);
        short8 o;
        const unsigned short* ap = (const unsigned short*)Arow;
#pragma unroll
        for (int i = 0; i < 8; ++i) o[i] = (kb + i < K) ? (short)ap[kb + i] : (short)0;
        return o;
    };
    auto cvtA = [&](const A8& a) -> f16x8 {
        f16x8 o;
#pragma unroll
        for (int i = 0; i < 4; ++i) {
            o[i]     = (_Float16)a.lo[i];
            o[4 + i] = (_Float16)a.hi[i];
        }
        return o;
    };

    // ---- prologue: stage phase 0, prefetch A(0..D-1) ----
    stageW(0);
    A8 ab[D]; short8 hb[D];
#pragma unroll
    for (int p = 0; p < D; ++p) {
        if (p < NS) {
            if constexpr (MODE == 0) ab[p] = loadA32(p);
            else                     hb[p] = loadA16(p);
        }
    }

    f32x4 ac[NFC], al[NFC];
#pragma unroll
    for (int f = 0; f < NFC; ++f) {
        ac[f] = (f32x4){0.f, 0.f, 0.f, 0.f};
        al[f] = (f32x4){0.f, 0.f, 0.f, 0.f};
    }

    __syncthreads();                           // phase-0 W resident

    const int ro = lr * 64 + ((kq ^ (lr & 3)) << 4);   // swizzled read offset

#pragma unroll
    for (int p = 0; p < NPH; ++p) {
#pragma unroll
        for (int sl = 0; sl < SPP; ++sl) {
            const int s = p * SPP + sl;        // compile-time after unroll
            f16x8 a0;
            if constexpr (MODE == 0) a0 = cvtA(ab[s % D]);
            else                     a0 = __builtin_bit_cast(f16x8, hb[s % D]);

            if (s + D < NS) {                  // refill consumed slot
                if constexpr (MODE == 0) ab[s % D] = loadA32(s + D);
                else                     hb[s % D] = loadA16(s + D);
            }

            const char* bb = lds + sl * SB;
#pragma unroll
            for (int f = 0; f < NFC; ++f) {
                f16x8 bh = __builtin_bit_cast(f16x8, *(const short8*)(bb + f * 1024 + ro));
                ac[f] = __builtin_amdgcn_mfma_f32_16x16x32_f16(a0, bh, ac[f], 0, 0, 0);
                if constexpr (HILO) {
                    f16x8 bl = __builtin_bit_cast(f16x8, *(const short8*)(bb + HB + f * 1024 + ro));
                    al[f] = __builtin_amdgcn_mfma_f32_16x16x32_f16(a0, bl, al[f], 0, 0, 0);
                }
            }
        }
        if (p + 1 < NPH) {                     // re-stage next K-phase
            __syncthreads();                   // all reads of phase p done
            stageW(p + 1);
            __syncthreads();                   // phase p+1 W resident
        }
    }

    // ---- store: D row=(lane>>4)*4+j, col=lane&15; scale dinv, cast fp16 ----
    const int rbase = m0 + wv * 16 + kq * 4;
    float dv[4];
#pragma unroll
    for (int j = 0; j < 4; ++j) {
        int row = rbase + j;
        dv[j] = (row < M) ? dinv[row] : 0.f;
    }
#pragma unroll
    for (int f = 0; f < NFC; ++f) {
        int col = col0 + f * 16 + lr;
        if (col >= Nout) continue;
#pragma unroll
        for (int j = 0; j < 4; ++j) {
            int row = rbase + j;
            if (row >= M) continue;
            float v = ac[f][j];
            if constexpr (HILO) v += al[f][j] * (1.0f / 2048.0f);
            H16[(size_t)row * ldh + col] = (_Float16)(v * dv[j]);
        }
    }
}

// ---------------- aggregation: out = dinv[d] * sum_e h16[src_e] + b -----------------
// wave-mapped (r18), 8-deep + 4-deep software-pipelined gather

template <int F, int VEC, bool RELU>
__global__ __launch_bounds__(256)
void agg_f16(const _Float16* __restrict__ h, const int* __restrict__ row_start,
             const int* __restrict__ csr_src, const float* __restrict__ dinv,
             const float* __restrict__ bias, _Float16* __restrict__ out, int n,
             int ldo) {
    constexpr int LPN = F / VEC;
    constexpr int NPW = 64 / LPN;
    int wave = blockIdx.x * 4 + (threadIdx.x >> 6);
    int lane = threadIdx.x & 63;
    int sub  = lane / LPN;
    int fi   = lane - sub * LPN;
    int node = wave * NPW + sub;
    if (sub >= NPW || node >= n) return;
    int f = fi * VEC;
    const _Float16* hf = h + f;

    f32x4 acc0 = {0.f, 0.f, 0.f, 0.f};
    f32x4 acc1 = {0.f, 0.f, 0.f, 0.f};

    auto addv = [&](const _Float16* p) {
        if constexpr (VEC == 8) {
            f16x8 v = *(const f16x8*)p;
            f16x4 vl, vh;
#pragma unroll
            for (int j = 0; j < 4; ++j) { vl[j] = v[j]; vh[j] = v[4 + j]; }
            acc0 += __builtin_convertvector(vl, f32x4);
            acc1 += __builtin_convertvector(vh, f32x4);
        } else {
            f16x4 v = *(const f16x4*)p;
            acc0 += __builtin_convertvector(v, f32x4);
        }
    };

    int e0 = row_start[node], e1 = row_start[node + 1];
    int e = e0;
    for (; e + 8 <= e1; e += 8) {
        int s0 = csr_src[e + 0], s1 = csr_src[e + 1];
        int s2 = csr_src[e + 2], s3 = csr_src[e + 3];
        int s4 = csr_src[e + 4], s5 = csr_src[e + 5];
        int s6 = csr_src[e + 6], s7 = csr_src[e + 7];
        const _Float16* p0 = &hf[(size_t)s0 * F];
        const _Float16* p1 = &hf[(size_t)s1 * F];
        const _Float16* p2 = &hf[(size_t)s2 * F];
        const _Float16* p3 = &hf[(size_t)s3 * F];
        const _Float16* p4 = &hf[(size_t)s4 * F];
        const _Float16* p5 = &hf[(size_t)s5 * F];
        const _Float16* p6 = &hf[(size_t)s6 * F];
        const _Float16* p7 = &hf[(size_t)s7 * F];
        addv(p0); addv(p1); addv(p2); addv(p3);
        addv(p4); addv(p5); addv(p6); addv(p7);
    }
    for (; e + 4 <= e1; e += 4) {
        int s0 = csr_src[e + 0], s1 = csr_src[e + 1];
        int s2 = csr_src[e + 2], s3 = csr_src[e + 3];
        const _Float16* p0 = &hf[(size_t)s0 * F];
        const _Float16* p1 = &hf[(size_t)s1 * F];
        const _Float16* p2 = &hf[(size_t)s2 * F];
        const _Float16* p3 = &hf[(size_t)s3 * F];
        addv(p0); addv(p1); addv(p2); addv(p3);
    }
    for (; e < e1; ++e) addv(&hf[(size_t)csr_src[e] * F]);

    float dn = dinv[node];
    if constexpr (VEC == 8) {
        f32x4 b0 = *(const f32x4*)&bias[f];
        f32x4 b1 = *(const f32x4*)&bias[f + 4];
        acc0 = acc0 * dn + b0;
        acc1 = acc1 * dn + b1;
        if (RELU) {
#pragma unroll
            for (int j = 0; j < 4; ++j) { acc0[j] = fmaxf(acc0[j], 0.f); acc1[j] = fmaxf(acc1[j], 0.f); }
        }
        f16x8 o;
#pragma unroll
        for (int j = 0; j < 4; ++j) { o[j] = (_Float16)acc0[j]; o[4 + j] = (_Float16)acc1[j]; }
        *(f16x8*)&out[(size_t)node * ldo + f] = o;
    } else {
        f32x4 b4 = *(const f32x4*)&bias[f];
        acc0 = acc0 * dn + b4;
        if (RELU) {
#pragma unroll
            for (int j = 0; j < 4; ++j) acc0[j] = fmaxf(acc0[j], 0.f);
        }
        f16x4 o;
#pragma unroll
        for (int j = 0; j < 4; ++j) o[j] = (_Float16)acc0[j];
        *(f16x4*)&out[(size_t)node * ldo + f] = o;
    }
}

// ---------------- tiny layer-4 helpers ----------------

__global__ void gemm_small(const _Float16* __restrict__ A, const float* __restrict__ B,
                           const float* __restrict__ dinv, float* __restrict__ C,
                           int M, int K) {
    int m = blockIdx.x * 256 + threadIdx.x;
    if (m >= M) return;
    float a0 = 0.f, a1 = 0.f, a2 = 0.f;
    for (int k = 0; k < K; ++k) {
        float a = (float)A[(size_t)m * K + k];
        a0 += a * B[0 * K + k];
        a1 += a * B[1 * K + k];
        a2 += a * B[2 * K + k];
    }
    float dv = dinv[m];
    C[(size_t)m * 3 + 0] = a0 * dv;
    C[(size_t)m * 3 + 1] = a1 * dv;
    C[(size_t)m * 3 + 2] = a2 * dv;
}

__global__ void agg_f3(const float* __restrict__ h, const int* __restrict__ row_start,
                       const int* __restrict__ csr_src, const float* __restrict__ dinv,
                       const float* __restrict__ bias, float* __restrict__ out, int n) {
    int i = blockIdx.x * 256 + threadIdx.x;
    if (i >= n * 3) return;
    int node = i / 3;
    int f = i - node * 3;
    float acc = 0.f;
    int e1 = row_start[node + 1];
    for (int e = row_start[node]; e < e1; ++e) {
        int s = csr_src[e];
        acc += h[(size_t)s * 3 + f];
    }
    out[i] = acc * dinv[node] + bias[f];
}

// ---------------------------------------------------------------------------

extern "C" void kernel_launch(void* const* d_in, const int* in_sizes, int n_in,
                              void* d_out, int out_size, void* d_ws, size_t ws_size,
                              hipStream_t stream) {
    const float* x   = (const float*)d_in[0];
    const int*   ei  = (const int*)d_in[1];
    const float* W1  = (const float*)d_in[2];
    const float* b1  = (const float*)d_in[3];
    const float* W1b = (const float*)d_in[4];
    const float* b1b = (const float*)d_in[5];
    const float* W2b = (const float*)d_in[6];
    const float* b2b = (const float*)d_in[7];
    const float* W2  = (const float*)d_in[8];
    const float* b2  = (const float*)d_in[9];
    float* out = (float*)d_out;

    const int F_IN = 500, H1 = 200, H2 = 100, H3 = 40;
    const int N = in_sizes[0] / F_IN;
    const int E = in_sizes[1] / 2;
    const int* src = ei;
    const int* dst = ei + E;

    size_t off = 0;
    auto alloc = [&](size_t bytes) -> void* {
        void* p = (char*)d_ws + off;
        off += (bytes + 255) & ~(size_t)255;
        return p;
    };
    int*   cnt       = (int*)  alloc((size_t)N * 4);
    int*   row_start = (int*)  alloc((size_t)(N + 1) * 4);
    int*   rank      = (int*)  alloc((size_t)E * 4);
    int*   partial   = (int*)  alloc(128 * 4);
    float* dinv      = (float*)alloc((size_t)N * 4);
    int*   csr_src   = (int*)  alloc((size_t)(E + N) * 4);
    unsigned short* wh1 = (unsigned short*)alloc(224 * 512 * 2);
    unsigned short* wh2 = (unsigned short*)alloc(128 * 256 * 2);
    unsigned short* wl2 = (unsigned short*)alloc(128 * 256 * 2);
    unsigned short* wh3 = (unsigned short*)alloc( 64 * 128 * 2);
    unsigned short* wl3 = (unsigned short*)alloc( 64 * 128 * 2);
    _Float16* h16   = (_Float16*)alloc((size_t)N * H1 * 2);
    _Float16* act16 = (_Float16*)alloc((size_t)N * H1 * 2);
    float*    bufC  = (float*)   alloc((size_t)N * 3 * 4);

    int gN = (N + 255) / 256;
    int nb = (N + 1023) / 1024;

    // --- prep: zero cnt, then fused count+rank / weight decompose ---
    hipMemsetAsync(cnt, 0, (size_t)N * 4, stream);
    {
        int total = E + 224 * 512 + 128 * 256 + 64 * 128;
        k_prep<<<(total + 255) / 256, 256, 0, stream>>>(dst, cnt, rank, E,
                                                        W1, wh1, W1b, wh2, wl2,
                                                        W2b, wh3, wl3);
    }
    k_scan1<<<nb, 256, 0, stream>>>(cnt, row_start, partial, dinv, N);
    k_scan2<<<1, 128, 0, stream>>>(partial, nb);
    k_scan3<<<gN, 256, 0, stream>>>(row_start, partial, N, E + N);

    const int gR = (N + 127) / 128;   // BM = 128

    // --- layer 1: 224-col block, 4 K-phases of 128 + FUSED csr fill ---
    gemm_res<14, 128, 4, 0, 0, 1, float><<<dim3(1, gR), 512, 0, stream>>>(
        x, F_IN, N, F_IN, wh1, wh1, dinv, h16, H1, H1,
        src, dst, row_start, cnt, rank, csr_src, E, N);
    {
        int waves = (N + 1) / 2, blocks = (waves + 3) / 4;   // NPW = 2
        agg_f16<200, 8, true><<<blocks, 256, 0, stream>>>(h16, row_start, csr_src, dinv,
                                                          b1, act16, N, 200);
    }
    // --- layer 2: 2 col-blocks of 64, W hi/lo, K padded 256, 2 phases ---
    gemm_res<4, 128, 2, 1, 1, 0, _Float16><<<dim3(2, gR), 512, 0, stream>>>(
        act16, 200, N, H1, wh2, wl2, dinv, h16, H2, H2,
        nullptr, nullptr, nullptr, nullptr, nullptr, nullptr, 0, 0);
    agg_f16<100, 4, true><<<(N / 2 + 3) / 4, 256, 0, stream>>>(h16, row_start, csr_src, dinv,
                                                               b1b, act16, N, 112);
    // --- layer 3: 1 col-block of 64, W hi/lo, single phase (A stride 112) ---
    gemm_res<4, 128, 1, 1, 1, 0, _Float16><<<dim3(1, gR), 512, 0, stream>>>(
        act16, 112, N, H2, wh3, wl3, dinv, h16, H3, H3,
        nullptr, nullptr, nullptr, nullptr, nullptr, nullptr, 0, 0);
    {
        int waves = (N + 11) / 12, blocks = (waves + 3) / 4;  // NPW = 12
        agg_f16<40, 8, true><<<blocks, 256, 0, stream>>>(h16, row_start, csr_src, dinv,
                                                         b2b, act16, N, 40);
    }
    // --- layer 4 ---
    gemm_small<<<(N + 255) / 256, 256, 0, stream>>>(act16, W2, dinv, bufC, N, H3);
    agg_f3<<<(N * 3 + 255) / 256, 256, 0, stream>>>(bufC, row_start, csr_src, dinv,
                                                    b2, out, N);
}